// Round 5
// baseline (320.352 us; speedup 1.0000x reference)
//
#include <hip/hip_runtime.h>

// Problem constants (from reference): B=16, S=4096, H=768, NUM_WORDS=2048.
constexpr int B = 16;
constexpr int S = 4096;
constexpr int H = 768;
constexpr int NW = 2048;
constexpr int V4 = H / 4;               // 192 float4 per token row
constexpr int T = 32;                   // tokens per wave chunk
constexpr int CPS = 128;                // chunks per sample
constexpr int WAVES_PER_BLK = 4;

__device__ __forceinline__ void acc4(float4& a, const float4 v) {
    a.x += v.x; a.y += v.y; a.z += v.z; a.w += v.w;
}

// One wave owns the 32-token chunk [t0, t0+32) and all words STARTING in it.
// The hot loop is 100% branch-free with a CONSTANT VMEM schedule: every token
// = 3 unconditional loads (ping-pong prefetched) + 3 unconditional stores
// (real output row iff this token ends a word, else a per-wave dummy row).
// Constant VMEM counts per path keep the waitcnt legalizer's counted vmcnt
// waits intact -- no vmcnt(0) drain in the loop (the failure mode of the
// previous rounds, where stores inside data-dependent branches forced
// conservative full drains and collapsed the pipeline).
__global__ __launch_bounds__(256, 2)
void seg_mean_kernel(const float* __restrict__ hs,
                     const int* __restrict__ wid,
                     float* __restrict__ out,
                     float* __restrict__ ws) {
    const int wave = threadIdx.x >> 6;
    const int lane = threadIdx.x & 63;
    const int gc = blockIdx.x * WAVES_PER_BLK + wave;  // global chunk id
    const int b = gc >> 7;                             // / CPS
    const int chunk = gc & (CPS - 1);
    const int t0 = 1 + chunk * T;                      // tokens 0, S-1 sentinels

    const int* __restrict__ wrow = wid + (size_t)b * S;

    // Control gather: lane l -> wid[t0-1+l] (clamped); lane 63 -> maxw.
    int gidx = t0 - 1 + lane;
    if (gidx > S - 1) gidx = S - 1;
    if (lane == 63) gidx = S - 2;
    const int wv = wrow[gidx];

    const float4* __restrict__ base = (const float4*)(hs + (size_t)b * S * H);
    float4* __restrict__ outb = (float4*)out;
    float4* const dummy = (float4*)ws + (size_t)(gc & 31) * V4;  // 96 KB scratch
    const int ob = b * NW;

    // Ping-pong groups of 4 tokens (12 float4 each).
#define GDECL(P) float4 P##0,P##1,P##2,P##3,P##4,P##5,P##6,P##7,P##8,P##9,P##10,P##11;
    GDECL(pA)
    GDECL(pB)
#define LD1(P, K, TT) { int t = (TT); if (t > S - 2) t = S - 2;            \
        const float4* p = base + (size_t)t * V4;                           \
        P##K = p[lane]; }
#define GISSUE(P, TB)                                                      \
    { int t=(TB);   if(t>S-2)t=S-2; const float4* p=base+(size_t)t*V4;     \
      P##0=p[lane]; P##1=p[lane+64]; P##2=p[lane+128]; }                   \
    { int t=(TB)+1; if(t>S-2)t=S-2; const float4* p=base+(size_t)t*V4;     \
      P##3=p[lane]; P##4=p[lane+64]; P##5=p[lane+128]; }                   \
    { int t=(TB)+2; if(t>S-2)t=S-2; const float4* p=base+(size_t)t*V4;     \
      P##6=p[lane]; P##7=p[lane+64]; P##8=p[lane+128]; }                   \
    { int t=(TB)+3; if(t>S-2)t=S-2; const float4* p=base+(size_t)t*V4;     \
      P##9=p[lane]; P##10=p[lane+64]; P##11=p[lane+128]; }

    GISSUE(pA, t0)
    GISSUE(pB, t0 + 4)
    __builtin_amdgcn_sched_barrier(0);

    const int maxw = __builtin_amdgcn_readlane(wv, 63);
    const int wprev = __shfl_up(wv, 1);
    const bool chg = (lane >= 1) && (lane <= 62) && (wv != wprev);
    const unsigned long long mask = __ballot(chg);  // bit l: token t0-1+l starts a word

    const float4 z = make_float4(0.f, 0.f, 0.f, 0.f);
    float4 a0 = z, a1 = z, a2 = z;
    bool valid = false;        // current word started in this chunk & is real
    int cnt = 0;               // tokens accumulated in current word
    int wval = -1;             // current word id (for extension walk)
    float4* wptr = dummy;      // current word's output row

    // Branch-free token step: uniform selects only; 3 unconditional stores.
#define STEP(J, RA, RB, RC) {                                              \
    const bool bnd = (mask >> ((J) + 1)) & 1ull;                           \
    const int wvj = __builtin_amdgcn_readlane(wv, (J) + 1);                \
    float4* const wcand = outb + (size_t)(ob + (wvj & (NW - 1))) * V4;     \
    wptr = bnd ? wcand : wptr;                                             \
    valid = bnd ? (wvj >= 0) : valid;                                      \
    wval = bnd ? wvj : wval;                                               \
    cnt = bnd ? 1 : cnt + 1;                                               \
    const float keep = bnd ? 0.0f : 1.0f;                                  \
    a0.x = fmaf(a0.x, keep, RA.x); a0.y = fmaf(a0.y, keep, RA.y);          \
    a0.z = fmaf(a0.z, keep, RA.z); a0.w = fmaf(a0.w, keep, RA.w);          \
    a1.x = fmaf(a1.x, keep, RB.x); a1.y = fmaf(a1.y, keep, RB.y);          \
    a1.z = fmaf(a1.z, keep, RB.z); a1.w = fmaf(a1.w, keep, RB.w);          \
    a2.x = fmaf(a2.x, keep, RC.x); a2.y = fmaf(a2.y, keep, RC.y);          \
    a2.z = fmaf(a2.z, keep, RC.z); a2.w = fmaf(a2.w, keep, RC.w);          \
    const bool is_last = (mask >> ((J) + 2)) & 1ull;                       \
    const float inv = 1.0f / (float)cnt;                                   \
    float4 m0, m1, m2;                                                     \
    m0.x=a0.x*inv; m0.y=a0.y*inv; m0.z=a0.z*inv; m0.w=a0.w*inv;            \
    m1.x=a1.x*inv; m1.y=a1.y*inv; m1.z=a1.z*inv; m1.w=a1.w*inv;            \
    m2.x=a2.x*inv; m2.y=a2.y*inv; m2.z=a2.z*inv; m2.w=a2.w*inv;            \
    float4* const sp = (is_last && valid) ? wptr : dummy;                  \
    sp[lane] = m0; sp[lane + 64] = m1; sp[lane + 128] = m2; }

#define GCONSUME(P, JB)                                                    \
    STEP((JB) + 0, P##0, P##1, P##2)                                       \
    STEP((JB) + 1, P##3, P##4, P##5)                                       \
    STEP((JB) + 2, P##6, P##7, P##8)                                       \
    STEP((JB) + 3, P##9, P##10, P##11)

    GCONSUME(pA, 0)
    GISSUE(pA, t0 + 8)
    __builtin_amdgcn_sched_barrier(0);
    GCONSUME(pB, 4)
    GISSUE(pB, t0 + 12)
    __builtin_amdgcn_sched_barrier(0);
    GCONSUME(pA, 8)
    GISSUE(pA, t0 + 16)
    __builtin_amdgcn_sched_barrier(0);
    GCONSUME(pB, 12)
    GISSUE(pB, t0 + 20)
    __builtin_amdgcn_sched_barrier(0);
    GCONSUME(pA, 16)
    GISSUE(pA, t0 + 24)
    __builtin_amdgcn_sched_barrier(0);
    GCONSUME(pB, 20)
    GISSUE(pB, t0 + 28)
    __builtin_amdgcn_sched_barrier(0);
    GCONSUME(pA, 24)
    GCONSUME(pB, 28)
#undef GCONSUME
#undef STEP
#undef GISSUE
#undef LD1
#undef GDECL

    // Extension: last owned word crosses the chunk end (branchy, post-pipeline).
    const bool closed = (mask >> 33) & 1ull;  // token t0+32 starts a new word
    if (valid && !closed) {
        int end_excl;
        const unsigned long long sh = (mask & 0x7fffffffffffffffull) >> 34;
        if (sh) {
            end_excl = t0 + 33 + __builtin_ctzll(sh);
        } else {
            int probe = t0 + 62;  // tokens t0+32..t0+61 confirmed same word
            while (true) {        // wid non-decreasing: first differing = end
                int tt = probe + lane;
                if (tt > S - 1) tt = S - 1;
                const int w2 = wrow[tt];
                const unsigned long long mm = __ballot(w2 != wval);
                if (mm) { end_excl = probe + __builtin_ctzll(mm); break; }
                probe += 64;
            }
        }
        cnt += end_excl - (t0 + 32);
        int t = t0 + 32;
        for (; t + 1 < end_excl; t += 2) {
            const float4* p0 = base + (size_t)t * V4;
            const float4* p1 = p0 + V4;
            float4 v0 = p0[lane], v1 = p0[lane + 64], v2 = p0[lane + 128];
            float4 u0 = p1[lane], u1 = p1[lane + 64], u2 = p1[lane + 128];
            acc4(a0, v0); acc4(a1, v1); acc4(a2, v2);
            acc4(a0, u0); acc4(a1, u1); acc4(a2, u2);
        }
        if (t < end_excl) {
            const float4* p = base + (size_t)t * V4;
            float4 v0 = p[lane], v1 = p[lane + 64], v2 = p[lane + 128];
            acc4(a0, v0); acc4(a1, v1); acc4(a2, v2);
        }
        const float inv = 1.0f / (float)cnt;
        float4 m0 = a0, m1 = a1, m2 = a2;
        m0.x *= inv; m0.y *= inv; m0.z *= inv; m0.w *= inv;
        m1.x *= inv; m1.y *= inv; m1.z *= inv; m1.w *= inv;
        m2.x *= inv; m2.y *= inv; m2.z *= inv; m2.w *= inv;
        wptr[lane] = m0; wptr[lane + 64] = m1; wptr[lane + 128] = m2;
    }

    // Zero-duty: words w > maxw get zero rows. 128 chunks x 16 words = 2048.
    {
        const int wz0 = chunk * 16;
#pragma unroll
        for (int k = 0; k < 16; ++k) {
            const int w = wz0 + k;
            if (w > maxw) {
                float4* o = outb + (size_t)(ob + w) * V4;
                o[lane] = z; o[lane + 64] = z; o[lane + 128] = z;
            }
        }
    }
}

extern "C" void kernel_launch(void* const* d_in, const int* in_sizes, int n_in,
                              void* d_out, int out_size, void* d_ws, size_t ws_size,
                              hipStream_t stream) {
    const float* hs = (const float*)d_in[0];
    const int* wid = (const int*)d_in[1];
    float* out = (float*)d_out;
    float* ws = (float*)d_ws;  // 32 dummy rows x 3 KB = 96 KB scratch

    seg_mean_kernel<<<(B * CPS) / WAVES_PER_BLK, 64 * WAVES_PER_BLK, 0, stream>>>(
        hs, wid, out, ws);
}

// Round 7
// 319.883 us; speedup vs baseline: 1.0015x; 1.0015x over previous
//
#include <hip/hip_runtime.h>

// Problem constants (from reference): B=16, S=4096, H=768, NUM_WORDS=2048.
constexpr int B = 16;
constexpr int S = 4096;
constexpr int H = 768;
constexpr int NW = 2048;
constexpr int V4 = H / 4;               // 192 float4 per token row
constexpr int T = 32;                   // tokens per wave chunk
constexpr int CPS = 128;                // chunks per sample
constexpr int WAVES_PER_BLK = 4;

typedef float f32x4 __attribute__((ext_vector_type(4)));

// One wave per 32-token chunk. The hot loop's memory schedule is written at
// ISA level: loads via inline-asm global_load_dwordx4 and EXPLICIT counted
// s_waitcnt vmcnt(N) (steady state vmcnt(24), never 0). Region op-counts are
// exact because the consume is branch-free with a CONSTANT 12 stores/group
// (dummy-row fallback); stores count in vmcnt and are included in the math.
// sched_barrier(0) fences (rule #18) keep compiler code from migrating
// across waits; "memory" clobbers pin its stores.
// (Round-6 resubmit: previous attempt died to container infra, no verdict.)
__global__ __launch_bounds__(256, 2)
void seg_mean_kernel(const float* __restrict__ hs,
                     const int* __restrict__ wid,
                     float* __restrict__ out,
                     float* __restrict__ ws) {
    const int wave = threadIdx.x >> 6;
    const int lane = threadIdx.x & 63;
    const int gc = blockIdx.x * WAVES_PER_BLK + wave;  // global chunk id
    const int b = gc >> 7;                             // / CPS
    const int chunk = gc & (CPS - 1);
    const int t0 = 1 + chunk * T;                      // tokens 0, S-1 sentinels

    const int* __restrict__ wrow = wid + (size_t)b * S;

    // ---- prologue control: fully materialized BEFORE any pipeline issue ----
    int gidx = t0 - 1 + lane;
    if (gidx > S - 1) gidx = S - 1;
    if (lane == 63) gidx = S - 2;
    const int wv = wrow[gidx];
    const int maxw = __builtin_amdgcn_readlane(wv, 63);
    const int wprev = __shfl_up(wv, 1);
    const bool chg = (lane >= 1) && (lane <= 62) && (wv != wprev);
    const unsigned long long mask = __ballot(chg);  // bit l: token t0-1+l starts a word
    __builtin_amdgcn_sched_barrier(0);

    const f32x4* __restrict__ bl = (const f32x4*)(hs + (size_t)b * S * H) + lane;
    f32x4* __restrict__ outb = (f32x4*)out;
    f32x4* const dum = (f32x4*)ws + (size_t)(gc & 31) * V4;  // 96 KB scratch
    const int ob = b * NW;

    const f32x4 zf = {0.f, 0.f, 0.f, 0.f};
    f32x4 a0 = zf, a1 = zf, a2 = zf;
    bool valid = false;
    int cnt = 0, wval = -1;
    f32x4* wptr = dum;

#define SB __builtin_amdgcn_sched_barrier(0)
#define VMWAIT(N) do { asm volatile("s_waitcnt vmcnt(" #N ")" ::: "memory"); SB; } while (0)
// 3 loads of one token row: base, +64, +128 f32x4 (offsets 1024/2048 bytes).
#define GL3(d0, d1, d2, ptr)                                               \
    asm volatile("global_load_dwordx4 %0, %3, off\n\t"                     \
                 "global_load_dwordx4 %1, %3, off offset:1024\n\t"         \
                 "global_load_dwordx4 %2, %3, off offset:2048"             \
                 : "=&v"(d0), "=&v"(d1), "=&v"(d2)                         \
                 : "v"(ptr))
#define ISSUE(P, TB) {                                                     \
    { int t = (TB) + 0; if (t > S - 2) t = S - 2;                          \
      GL3(P##0, P##1, P##2, bl + (size_t)t * V4); }                        \
    { int t = (TB) + 1; if (t > S - 2) t = S - 2;                          \
      GL3(P##3, P##4, P##5, bl + (size_t)t * V4); }                        \
    { int t = (TB) + 2; if (t > S - 2) t = S - 2;                          \
      GL3(P##6, P##7, P##8, bl + (size_t)t * V4); }                        \
    { int t = (TB) + 3; if (t > S - 2) t = S - 2;                          \
      GL3(P##9, P##10, P##11, bl + (size_t)t * V4); } }

    f32x4 e0,e1,e2,e3,e4,e5,e6,e7,e8,e9,e10,e11;
    f32x4 o0,o1,o2,o3,o4,o5,o6,o7,o8,o9,o10,o11;

// Branch-free token step: uniform selects, exactly 3 unconditional stores.
#define STEP(J, RA, RB, RC) {                                              \
    const bool bnd = (mask >> ((J) + 1)) & 1ull;                           \
    const int wvj = __builtin_amdgcn_readlane(wv, (J) + 1);                \
    f32x4* const wcand = outb + (size_t)(ob + (wvj & (NW - 1))) * V4;      \
    wptr = bnd ? wcand : wptr;                                             \
    valid = bnd ? (wvj >= 0) : valid;                                      \
    wval = bnd ? wvj : wval;                                               \
    cnt = bnd ? 1 : cnt + 1;                                               \
    const float keep = bnd ? 0.0f : 1.0f;                                  \
    a0 = a0 * keep + RA; a1 = a1 * keep + RB; a2 = a2 * keep + RC;         \
    const bool is_last = (mask >> ((J) + 2)) & 1ull;                       \
    const float inv = 1.0f / (float)cnt;                                   \
    f32x4 m0 = a0 * inv, m1 = a1 * inv, m2 = a2 * inv;                     \
    f32x4* const sp = (is_last && valid) ? wptr : dum;                     \
    sp[lane] = m0; sp[lane + 64] = m1; sp[lane + 128] = m2; }
#define CONS(P, JB)                                                        \
    STEP((JB) + 0, P##0, P##1, P##2)                                       \
    STEP((JB) + 1, P##3, P##4, P##5)                                       \
    STEP((JB) + 2, P##6, P##7, P##8)                                       \
    STEP((JB) + 3, P##9, P##10, P##11)

    // ---- manual pipeline: groups g0..g7 of 4 tokens; 2-deep ping-pong ----
    ISSUE(e, t0 + 0)      // g0
    ISSUE(o, t0 + 4)      // g1
    SB;
    VMWAIT(12); CONS(e, 0)  SB; ISSUE(e, t0 + 8)  SB;   // R0: St(g0)+I(g2)
    VMWAIT(24); CONS(o, 4)  SB; ISSUE(o, t0 + 12) SB;   // R1: St(g1)+I(g3)
    VMWAIT(24); CONS(e, 8)  SB; ISSUE(e, t0 + 16) SB;   // R2
    VMWAIT(24); CONS(o, 12) SB; ISSUE(o, t0 + 20) SB;   // R3
    VMWAIT(24); CONS(e, 16) SB; ISSUE(e, t0 + 24) SB;   // R4
    VMWAIT(24); CONS(o, 20) SB; ISSUE(o, t0 + 28) SB;   // R5
    VMWAIT(24); CONS(e, 24) SB;                         // R6: St(g6) only
    VMWAIT(12); CONS(o, 28)                             // R7
#undef CONS
#undef STEP
#undef ISSUE
#undef GL3
#undef VMWAIT

    // ---- extension: last owned word crosses the chunk end (rare, branchy) ----
    const bool closed = (mask >> 33) & 1ull;  // token t0+32 starts a new word
    if (valid && !closed) {
        int end_excl;
        const unsigned long long sh = (mask & 0x7fffffffffffffffull) >> 34;
        if (sh) {
            end_excl = t0 + 33 + __builtin_ctzll(sh);
        } else {
            int probe = t0 + 62;  // tokens t0+32..t0+61 confirmed same word
            while (true) {        // wid non-decreasing: first differing = end
                int tt = probe + lane;
                if (tt > S - 1) tt = S - 1;
                const int w2 = wrow[tt];
                const unsigned long long mm = __ballot(w2 != wval);
                if (mm) { end_excl = probe + __builtin_ctzll(mm); break; }
                probe += 64;
            }
        }
        cnt += end_excl - (t0 + 32);
        int t = t0 + 32;
        for (; t + 1 < end_excl; t += 2) {
            const f32x4* p0 = bl + (size_t)t * V4;
            const f32x4* p1 = p0 + V4;
            f32x4 v0 = p0[0], v1 = p0[64], v2 = p0[128];
            f32x4 u0 = p1[0], u1 = p1[64], u2 = p1[128];
            a0 += v0; a1 += v1; a2 += v2;
            a0 += u0; a1 += u1; a2 += u2;
        }
        if (t < end_excl) {
            const f32x4* p = bl + (size_t)t * V4;
            a0 += p[0]; a1 += p[64]; a2 += p[128];
        }
        const float inv = 1.0f / (float)cnt;
        f32x4 m0 = a0 * inv, m1 = a1 * inv, m2 = a2 * inv;
        wptr[lane] = m0; wptr[lane + 64] = m1; wptr[lane + 128] = m2;
    }

    // ---- zero-duty: words w > maxw get zero rows (128 chunks x 16 = 2048) ----
    {
        const int wz0 = chunk * 16;
#pragma unroll
        for (int k = 0; k < 16; ++k) {
            const int w = wz0 + k;
            if (w > maxw) {
                f32x4* o = outb + (size_t)(ob + w) * V4;
                o[lane] = zf; o[lane + 64] = zf; o[lane + 128] = zf;
            }
        }
    }
#undef SB
}

extern "C" void kernel_launch(void* const* d_in, const int* in_sizes, int n_in,
                              void* d_out, int out_size, void* d_ws, size_t ws_size,
                              hipStream_t stream) {
    const float* hs = (const float*)d_in[0];
    const int* wid = (const int*)d_in[1];
    float* out = (float*)d_out;
    float* ws = (float*)d_ws;  // 32 dummy rows x 3 KB = 96 KB scratch

    seg_mean_kernel<<<(B * CPS) / WAVES_PER_BLK, 64 * WAVES_PER_BLK, 0, stream>>>(
        hs, wid, out, ws);
}

// Round 8
// 311.824 us; speedup vs baseline: 1.0273x; 1.0258x over previous
//
#include <hip/hip_runtime.h>

// Problem constants (from reference): B=16, S=4096, H=768, NUM_WORDS=2048.
constexpr int B = 16;
constexpr int S = 4096;
constexpr int H = 768;
constexpr int NW = 2048;
constexpr int V4 = H / 4;               // 192 f32x4 per token row
constexpr int W = 8;                    // tokens per wave window
constexpr int WPS = 512;                // windows per sample
constexpr int WAVES_PER_BLK = 4;

typedef float f32x4 __attribute__((ext_vector_type(4)));

// Round-3 structure (best measured: one-shot 24 named-register loads per
// 8-token window, sched_barrier-pinned) with ONE change: all output stores
// are NONTEMPORAL. Theory: our cached write stream (96 MiB/iter) was
// evicting hidden_states from the 256 MiB Infinity Cache between bench
// iterations (FETCH_SIZE showed only half of hs hitting); NT stores stop
// polluting L3 so reads serve at IF-cache latency instead of loaded-HBM
// latency.
__global__ __launch_bounds__(256)
void seg_mean_kernel(const float* __restrict__ hs,
                     const int* __restrict__ wid,
                     float* __restrict__ out) {
    const int wave = threadIdx.x >> 6;
    const int lane = threadIdx.x & 63;
    const int gwin = blockIdx.x * WAVES_PER_BLK + wave;
    const int b = gwin >> 9;                 // / WPS
    const int win = gwin & (WPS - 1);
    const int t0 = 1 + win * W;              // tokens 0 and S-1 are sentinels

    const int* __restrict__ wrow = wid + (size_t)b * S;

    // wid gather FIRST (oldest outstanding -> its wait leaves token loads in
    // flight). Lanes 0..62: wid[t0-1+lane] (clamped); lane 63: maxw.
    int gidx = t0 - 1 + lane;
    if (gidx > S - 1) gidx = S - 1;
    if (lane == 63) gidx = S - 2;
    const int wv = wrow[gidx];

    // 24 token-row loads, individually named, issued back-to-back.
    const f32x4* __restrict__ bl = (const f32x4*)(hs + (size_t)b * S * H) + lane;
#define TOKS(X) X(0) X(1) X(2) X(3) X(4) X(5) X(6) X(7)
#define DECL(J) f32x4 rA##J, rB##J, rC##J;
    TOKS(DECL)
#define LOADTOK(J) { int t = t0 + J; if (t > S - 2) t = S - 2;              \
        const f32x4* p = bl + (size_t)t * V4;                              \
        rA##J = p[0]; rB##J = p[64]; rC##J = p[128]; }
    TOKS(LOADTOK)
    __builtin_amdgcn_sched_barrier(0);  // loads stay above, consumes below

    const int maxw = __builtin_amdgcn_readlane(wv, 63);

    // boundary mask: bit l (1..62) => token (t0-1+l) has wid != previous token
    const int wprev = __shfl_up(wv, 1);
    const bool chg = (lane >= 1) && (lane <= 62) && (wv != wprev);
    const unsigned long long mask = __ballot(chg);

    const f32x4 z = {0.f, 0.f, 0.f, 0.f};
    f32x4 a0 = z, a1 = z, a2 = z;
    int cnt = 0, wcur = 0;
    bool active = false;

    auto flush = [&]() {
        const float inv = 1.0f / (float)cnt;
        f32x4 m0 = a0 * inv, m1 = a1 * inv, m2 = a2 * inv;
        f32x4* o = (f32x4*)(out + ((size_t)b * NW + wcur) * H) + lane;
        __builtin_nontemporal_store(m0, o);
        __builtin_nontemporal_store(m1, o + 64);
        __builtin_nontemporal_store(m2, o + 128);
    };

    // window steps: token t0+J <-> mask bit J+1 <-> wv lane J+1
#define STEP(J) {                                                          \
        if ((mask >> (J + 1)) & 1ull) {                                    \
            if (active) flush();                                           \
            const int wval = __builtin_amdgcn_readlane(wv, J + 1);         \
            active = (wval >= 0);                                          \
            if (active) { wcur = wval; a0 = z; a1 = z; a2 = z; cnt = 0; }  \
        }                                                                  \
        if (active) { a0 += rA##J; a1 += rB##J; a2 += rC##J; ++cnt; } }
    TOKS(STEP)
#undef STEP
#undef LOADTOK
#undef DECL
#undef TOKS

    // extension: last owned word crosses the window end
    if (active) {
        int end;
        const unsigned long long hi = mask >> 9;  // bits for tokens t0+8..t0+61
        if (hi) {
            end = t0 + 8 + __builtin_ctzll(hi);
        } else {
            end = t0 + 62;  // tokens t0+8..t0+61 confirmed same word
            while (true) {  // wid is non-decreasing: first differing = word end
                int t = end + lane;
                if (t > S - 1) t = S - 1;
                const int wv2 = wrow[t];
                const unsigned long long m2 = __ballot(wv2 != wcur);
                if (m2) { end += __builtin_ctzll(m2); break; }
                end += 64;
            }
        }
        cnt += end - (t0 + 8);
        int t = t0 + 8;
        for (; t + 3 < end; t += 4) {  // 12 independent loads per iteration
            const f32x4* p0 = bl + (size_t)t * V4;
            const f32x4* p1 = p0 + V4;
            const f32x4* p2 = p1 + V4;
            const f32x4* p3 = p2 + V4;
            f32x4 x00 = p0[0], x01 = p0[64], x02 = p0[128];
            f32x4 x10 = p1[0], x11 = p1[64], x12 = p1[128];
            f32x4 x20 = p2[0], x21 = p2[64], x22 = p2[128];
            f32x4 x30 = p3[0], x31 = p3[64], x32 = p3[128];
            a0 += x00; a1 += x01; a2 += x02;
            a0 += x10; a1 += x11; a2 += x12;
            a0 += x20; a1 += x21; a2 += x22;
            a0 += x30; a1 += x31; a2 += x32;
        }
        for (; t < end; ++t) {
            const f32x4* p = bl + (size_t)t * V4;
            a0 += p[0]; a1 += p[64]; a2 += p[128];
        }
        flush();
    }

    // zero-duty: words w > maxw are never produced -> write zero rows.
    // 512 windows x 4 words cover all 2048 word slots of this sample.
    {
        const int wz0 = win * 4;
#pragma unroll
        for (int k = 0; k < 4; ++k) {
            const int w = wz0 + k;
            if (w > maxw) {
                f32x4* o = (f32x4*)(out + ((size_t)b * NW + w) * H) + lane;
                __builtin_nontemporal_store(z, o);
                __builtin_nontemporal_store(z, o + 64);
                __builtin_nontemporal_store(z, o + 128);
            }
        }
    }
}

extern "C" void kernel_launch(void* const* d_in, const int* in_sizes, int n_in,
                              void* d_out, int out_size, void* d_ws, size_t ws_size,
                              hipStream_t stream) {
    const float* hs = (const float*)d_in[0];
    const int* wid = (const int*)d_in[1];
    float* out = (float*)d_out;

    seg_mean_kernel<<<(B * WPS) / WAVES_PER_BLK, 64 * WAVES_PER_BLK, 0, stream>>>(
        hs, wid, out);
}